// Round 4
// baseline (239.196 us; speedup 1.0000x reference)
//
#include <hip/hip_runtime.h>

#define DIN 256
#define DOUT 64
#define SCAN_BLK 256
#define BUCKET_BITS 14
#define BUCKET (1 << BUCKET_BITS)   // 16384 nodes per LDS bucket (64 KB)
#define CHUNKS 16

// ---------------- histogram: per-(chunk,bucket,array) LDS-private counts ----------------
// grid = (CHUNKS, n_buckets, 2); z=0 -> src (outdeg), z=1 -> dst (indeg)
__global__ __launch_bounds__(256) void hist_kernel(
    const int* __restrict__ src, const int* __restrict__ dst,
    int* __restrict__ part, int n_nodes, int n_edges, int n_pad)
{
    __shared__ int cnt[BUCKET];
    const int c = blockIdx.x, b = blockIdx.y, a = blockIdx.z;
    const int* __restrict__ idx = a ? dst : src;
    const int base = b << BUCKET_BITS;

    for (int i = threadIdx.x; i < BUCKET; i += 256) cnt[i] = 0;
    __syncthreads();

    const int ebeg = (int)((long long)n_edges * c / CHUNKS);
    const int eend = (int)((long long)n_edges * (c + 1) / CHUNKS);
    for (int e = ebeg + threadIdx.x; e < eend; e += 256) {
        unsigned v = (unsigned)(idx[e] - base);
        if (v < (unsigned)BUCKET) atomicAdd(&cnt[v], 1);
    }
    __syncthreads();

    const int lim = min(BUCKET, n_nodes - base);
    int* row = part + ((size_t)(a * CHUNKS + c)) * n_pad + base;
    for (int i = threadIdx.x; i < lim; i += 256) row[i] = cnt[i];
}

// ---------------- reduce partials -> outdeg, indeg, per-chunk excl prefix cb ----------------
__global__ __launch_bounds__(256) void reduce_deg_kernel(
    const int* __restrict__ part, int* __restrict__ outdeg,
    int* __restrict__ indeg, int* __restrict__ cb, int n_nodes, int n_pad)
{
    int i = blockIdx.x * 256 + threadIdx.x;
    if (i >= n_nodes) return;
    int s0 = 0;
    #pragma unroll
    for (int c = 0; c < CHUNKS; ++c) s0 += part[(size_t)c * n_pad + i];
    outdeg[i] = s0;
    int run = 0;
    #pragma unroll
    for (int c = 0; c < CHUNKS; ++c) {
        cb[(size_t)c * n_pad + i] = run;
        run += part[(size_t)(CHUNKS + c) * n_pad + i];
    }
    indeg[i] = run;
}

// ---------------- scan phase 1: per-block sums ----------------
__global__ __launch_bounds__(SCAN_BLK) void partial_kernel(
    const int* __restrict__ indeg, int* __restrict__ bsum, int n)
{
    __shared__ int red[SCAN_BLK / 64];
    int idx = blockIdx.x * SCAN_BLK + threadIdx.x;
    int v = (idx < n) ? indeg[idx] : 0;
    #pragma unroll
    for (int off = 32; off >= 1; off >>= 1)
        v += __shfl_down(v, off, 64);
    int wid = threadIdx.x >> 6;
    if ((threadIdx.x & 63) == 0) red[wid] = v;
    __syncthreads();
    if (threadIdx.x == 0) {
        int s = 0;
        #pragma unroll
        for (int w = 0; w < SCAN_BLK / 64; ++w) s += red[w];
        bsum[blockIdx.x] = s;
    }
}

// ---------------- scan phase 2: exclusive scan of block sums (1 block) ----------------
__global__ __launch_bounds__(256) void scan_bsums_kernel(
    int* __restrict__ bsum, int* __restrict__ boff, int nblocks)
{
    __shared__ int s[256];
    int t = threadIdx.x;
    int v = (t < nblocks) ? bsum[t] : 0;
    s[t] = v;
    __syncthreads();
    for (int off = 1; off < 256; off <<= 1) {
        int u = 0;
        if (t >= off) u = s[t - off];
        __syncthreads();
        if (t >= off) s[t] += u;
        __syncthreads();
    }
    if (t < nblocks) boff[t] = s[t] - v;  // exclusive
}

// ---------------- scan phase 3: emit rowptr, add rowptr into cb rows ----------------
__global__ __launch_bounds__(SCAN_BLK) void emit_kernel(
    const int* __restrict__ indeg, const int* __restrict__ boff,
    int* __restrict__ rowptr, int* __restrict__ cb,
    int n, int n_edges, int n_pad)
{
    __shared__ int s[SCAN_BLK];
    int t = threadIdx.x;
    int idx = blockIdx.x * SCAN_BLK + t;
    int v = (idx < n) ? indeg[idx] : 0;
    s[t] = v;
    __syncthreads();
    for (int off = 1; off < SCAN_BLK; off <<= 1) {
        int u = 0;
        if (t >= off) u = s[t - off];
        __syncthreads();
        if (t >= off) s[t] += u;
        __syncthreads();
    }
    if (idx < n) {
        int excl = boff[blockIdx.x] + s[t] - v;
        rowptr[idx] = excl;
        #pragma unroll
        for (int c = 0; c < CHUNKS; ++c)
            cb[(size_t)c * n_pad + idx] += excl;
    }
    if (idx == 0) rowptr[n] = n_edges;
}

// ---------------- CSR fill via LDS cursor multisplit ----------------
// grid = (CHUNKS, n_buckets)
__global__ __launch_bounds__(256) void fill_kernel(
    const int* __restrict__ src, const int* __restrict__ dst,
    const int* __restrict__ cb, int* __restrict__ col,
    int n_nodes, int n_edges, int n_pad)
{
    __shared__ int cur[BUCKET];
    const int c = blockIdx.x, b = blockIdx.y;
    const int base = b << BUCKET_BITS;
    const int lim = min(BUCKET, n_nodes - base);

    const int* cbrow = cb + (size_t)c * n_pad + base;
    for (int i = threadIdx.x; i < lim; i += 256) cur[i] = cbrow[i];
    __syncthreads();

    const int ebeg = (int)((long long)n_edges * c / CHUNKS);
    const int eend = (int)((long long)n_edges * (c + 1) / CHUNKS);
    for (int e = ebeg + threadIdx.x; e < eend; e += 256) {
        unsigned v = (unsigned)(dst[e] - base);
        if (v < (unsigned)BUCKET) {
            int pos = atomicAdd(&cur[v], 1);
            col[pos] = src[e];
        }
    }
}

// ---------------- GEMM: h = (x * norm_src) @ W ----------------
__global__ __launch_bounds__(256) void gemm_norm_kernel(
    const float* __restrict__ x, const float* __restrict__ W,
    const int* __restrict__ outdeg, float* __restrict__ h, int n_nodes)
{
    __shared__ float xs[64][68];
    __shared__ float wt[64][68];

    const int tid = threadIdx.x;
    const int ty = tid >> 4;
    const int tx = tid & 15;
    const int r0 = blockIdx.x * 64;

    float acc[4][4] = {};

    for (int k0 = 0; k0 < DIN; k0 += 64) {
        #pragma unroll
        for (int i = 0; i < 4; ++i) {
            int row = (tid >> 4) + 16 * i;
            int c4  = tid & 15;
            int grow = r0 + row;
            float4 v = make_float4(0.f, 0.f, 0.f, 0.f);
            if (grow < n_nodes)
                v = *reinterpret_cast<const float4*>(&x[(size_t)grow * DIN + k0 + c4 * 4]);
            *reinterpret_cast<float4*>(&xs[row][c4 * 4]) = v;
        }
        #pragma unroll
        for (int i = 0; i < 4; ++i) {
            int krow = (tid >> 4) + 16 * i;
            int c4   = tid & 15;
            float4 v = *reinterpret_cast<const float4*>(&W[(size_t)(k0 + krow) * DOUT + c4 * 4]);
            *reinterpret_cast<float4*>(&wt[krow][c4 * 4]) = v;
        }
        __syncthreads();

        #pragma unroll
        for (int k = 0; k < 64; ++k) {
            float a[4], bb[4];
            #pragma unroll
            for (int i = 0; i < 4; ++i) a[i] = xs[ty * 4 + i][k];
            #pragma unroll
            for (int j = 0; j < 4; ++j) bb[j] = wt[k][tx * 4 + j];
            #pragma unroll
            for (int i = 0; i < 4; ++i)
                #pragma unroll
                for (int j = 0; j < 4; ++j)
                    acc[i][j] = fmaf(a[i], bb[j], acc[i][j]);
        }
        __syncthreads();
    }

    #pragma unroll
    for (int i = 0; i < 4; ++i) {
        int grow = r0 + ty * 4 + i;
        if (grow >= n_nodes) continue;
        float ns = rsqrtf(fmaxf((float)outdeg[grow], 1.0f));
        float4 v = make_float4(acc[i][0] * ns, acc[i][1] * ns, acc[i][2] * ns, acc[i][3] * ns);
        *reinterpret_cast<float4*>(&h[(size_t)grow * DOUT + tx * 4]) = v;
    }
}

// ---------------- gather + finalize: one wave per dst node, lane = column ----------------
__global__ __launch_bounds__(256) void gather_kernel(
    const float* __restrict__ h, const int* __restrict__ rowptr,
    const int* __restrict__ col, const float* __restrict__ bias,
    float* __restrict__ out, int n_nodes)
{
    int wave = (blockIdx.x * blockDim.x + threadIdx.x) >> 6;
    int lane = threadIdx.x & 63;
    if (wave >= n_nodes) return;

    const int beg = rowptr[wave];
    const int end = rowptr[wave + 1];
    const int deg = end - beg;

    float acc = 0.f;
    int i = beg;
    for (; i + 4 <= end; i += 4) {
        int s0 = col[i], s1 = col[i + 1], s2 = col[i + 2], s3 = col[i + 3];
        float v0 = h[(size_t)s0 * DOUT + lane];
        float v1 = h[(size_t)s1 * DOUT + lane];
        float v2 = h[(size_t)s2 * DOUT + lane];
        float v3 = h[(size_t)s3 * DOUT + lane];
        acc += (v0 + v1) + (v2 + v3);
    }
    for (; i < end; ++i) {
        acc += h[(size_t)col[i] * DOUT + lane];
    }

    float nd = rsqrtf(fmaxf((float)deg, 1.0f));
    out[(size_t)wave * DOUT + lane] = fmaxf(fmaf(acc, nd, bias[lane]), 0.f);
}

extern "C" void kernel_launch(void* const* d_in, const int* in_sizes, int n_in,
                              void* d_out, int out_size, void* d_ws, size_t ws_size,
                              hipStream_t stream) {
    const float* x   = (const float*)d_in[0];
    const float* W   = (const float*)d_in[1];
    const float* b   = (const float*)d_in[2];
    const int*   src = (const int*)d_in[3];
    const int*   dst = (const int*)d_in[4];
    float* out = (float*)d_out;

    const int n_nodes = in_sizes[0] / DIN;   // 50000
    const int n_edges = in_sizes[3];         // 800000
    const int nsb = (n_nodes + SCAN_BLK - 1) / SCAN_BLK;         // 196
    const int nbuck = (n_nodes + BUCKET - 1) >> BUCKET_BITS;     // 4
    const int n_pad = ((n_nodes + 255) / 256) * 256;             // 50176

    // workspace layout
    int* outdeg = (int*)d_ws;                  // n
    int* indeg  = outdeg + n_nodes;            // n
    int* rowptr = indeg + n_nodes;             // n+1
    int* bsum   = rowptr + n_nodes + 1;        // 256
    int* boff   = bsum + 256;                  // 256
    int* col    = boff + 256;                  // n_edges
    size_t int_count = (size_t)3 * n_nodes + 1 + 512 + n_edges;
    size_t h_off = ((int_count * sizeof(int) + 15) / 16) * 16;
    float* h = (float*)((char*)d_ws + h_off);  // n*64 floats (12.8 MB)

    // partials + cursor-base alias the h region (consumed before gemm writes h)
    int* part = (int*)h;                            // 2*CHUNKS*n_pad ints (6.4 MB)
    int* cb   = part + (size_t)2 * CHUNKS * n_pad;  // CHUNKS*n_pad ints (3.2 MB)

    hist_kernel<<<dim3(CHUNKS, nbuck, 2), 256, 0, stream>>>(src, dst, part, n_nodes, n_edges, n_pad);
    reduce_deg_kernel<<<(n_nodes + 255) / 256, 256, 0, stream>>>(part, outdeg, indeg, cb, n_nodes, n_pad);
    partial_kernel<<<nsb, SCAN_BLK, 0, stream>>>(indeg, bsum, n_nodes);
    scan_bsums_kernel<<<1, 256, 0, stream>>>(bsum, boff, nsb);
    emit_kernel<<<nsb, SCAN_BLK, 0, stream>>>(indeg, boff, rowptr, cb, n_nodes, n_edges, n_pad);
    fill_kernel<<<dim3(CHUNKS, nbuck), 256, 0, stream>>>(src, dst, cb, col, n_nodes, n_edges, n_pad);
    gemm_norm_kernel<<<(n_nodes + 63) / 64, 256, 0, stream>>>(x, W, outdeg, h, n_nodes);
    gather_kernel<<<((size_t)n_nodes * 64 + 255) / 256, 256, 0, stream>>>(h, rowptr, col, b, out, n_nodes);
}

// Round 5
// 147.514 us; speedup vs baseline: 1.6215x; 1.6215x over previous
//
#include <hip/hip_runtime.h>

#define DIN 256
#define DOUT 64
#define SCAN_BLK 256
#define BUCKET_BITS 14
#define BUCKET (1 << BUCKET_BITS)   // 16384 nodes per LDS bucket (64 KB)
#define CHUNKS 64                   // edge chunks -> fill grid = CHUNKS x nbuck = 256 blocks

// ---------------- histogram: per-(chunk,bucket,array) LDS-private counts -> u16 partials ----------------
// grid = (CHUNKS, n_buckets, 2); z=0 -> src (outdeg), z=1 -> dst (indeg)
__global__ __launch_bounds__(256) void hist_kernel(
    const int* __restrict__ src, const int* __restrict__ dst,
    unsigned short* __restrict__ part, int n_nodes, int n_edges, int n_pad)
{
    __shared__ int cnt[BUCKET];
    const int c = blockIdx.x, b = blockIdx.y, a = blockIdx.z;
    const int* __restrict__ idx = a ? dst : src;
    const int base = b << BUCKET_BITS;

    for (int i = threadIdx.x; i < BUCKET; i += 256) cnt[i] = 0;
    __syncthreads();

    const int ebeg = (int)((long long)n_edges * c / CHUNKS);
    const int eend = (int)((long long)n_edges * (c + 1) / CHUNKS);
    for (int e = ebeg + threadIdx.x; e < eend; e += 256) {
        unsigned v = (unsigned)(idx[e] - base);
        if (v < (unsigned)BUCKET) atomicAdd(&cnt[v], 1);
    }
    __syncthreads();

    const int lim = min(BUCKET, n_nodes - base);
    unsigned short* row = part + (size_t)(a * CHUNKS + c) * n_pad + base;
    for (int i = threadIdx.x; i < lim; i += 256) row[i] = (unsigned short)cnt[i];
}

// ---------------- reduce partials -> outdeg; in-place excl prefix over dst rows -> indeg ----------------
__global__ __launch_bounds__(256) void reduce_deg_kernel(
    unsigned short* __restrict__ part, int* __restrict__ outdeg,
    int* __restrict__ indeg, int n_nodes, int n_pad)
{
    int i = blockIdx.x * 256 + threadIdx.x;
    if (i >= n_nodes) return;
    int s0 = 0;
    #pragma unroll
    for (int c = 0; c < CHUNKS; ++c) s0 += part[(size_t)c * n_pad + i];
    outdeg[i] = s0;
    int run = 0;
    #pragma unroll
    for (int c = 0; c < CHUNKS; ++c) {
        size_t off = (size_t)(CHUNKS + c) * n_pad + i;
        int t = part[off];
        part[off] = (unsigned short)run;   // becomes per-chunk exclusive base (fits u16: <= indeg)
        run += t;
    }
    indeg[i] = run;
}

// ---------------- scan phase 1: per-block sums ----------------
__global__ __launch_bounds__(SCAN_BLK) void partial_kernel(
    const int* __restrict__ indeg, int* __restrict__ bsum, int n)
{
    __shared__ int red[SCAN_BLK / 64];
    int idx = blockIdx.x * SCAN_BLK + threadIdx.x;
    int v = (idx < n) ? indeg[idx] : 0;
    #pragma unroll
    for (int off = 32; off >= 1; off >>= 1)
        v += __shfl_down(v, off, 64);
    int wid = threadIdx.x >> 6;
    if ((threadIdx.x & 63) == 0) red[wid] = v;
    __syncthreads();
    if (threadIdx.x == 0) {
        int s = 0;
        #pragma unroll
        for (int w = 0; w < SCAN_BLK / 64; ++w) s += red[w];
        bsum[blockIdx.x] = s;
    }
}

// ---------------- scan phase 2: exclusive scan of block sums (1 block) ----------------
__global__ __launch_bounds__(256) void scan_bsums_kernel(
    int* __restrict__ bsum, int* __restrict__ boff, int nblocks)
{
    __shared__ int s[256];
    int t = threadIdx.x;
    int v = (t < nblocks) ? bsum[t] : 0;
    s[t] = v;
    __syncthreads();
    for (int off = 1; off < 256; off <<= 1) {
        int u = 0;
        if (t >= off) u = s[t - off];
        __syncthreads();
        if (t >= off) s[t] += u;
        __syncthreads();
    }
    if (t < nblocks) boff[t] = s[t] - v;  // exclusive
}

// ---------------- scan phase 3: emit rowptr ----------------
__global__ __launch_bounds__(SCAN_BLK) void emit_kernel(
    const int* __restrict__ indeg, const int* __restrict__ boff,
    int* __restrict__ rowptr, int n, int n_edges)
{
    __shared__ int s[SCAN_BLK];
    int t = threadIdx.x;
    int idx = blockIdx.x * SCAN_BLK + t;
    int v = (idx < n) ? indeg[idx] : 0;
    s[t] = v;
    __syncthreads();
    for (int off = 1; off < SCAN_BLK; off <<= 1) {
        int u = 0;
        if (t >= off) u = s[t - off];
        __syncthreads();
        if (t >= off) s[t] += u;
        __syncthreads();
    }
    if (idx < n) rowptr[idx] = boff[blockIdx.x] + s[t] - v;
    if (idx == 0) rowptr[n] = n_edges;
}

// ---------------- CSR fill via LDS cursor multisplit ----------------
// grid = (CHUNKS, n_buckets); cursor = rowptr[v] + per-chunk prefix (from part, in-place)
__global__ __launch_bounds__(256) void fill_kernel(
    const int* __restrict__ src, const int* __restrict__ dst,
    const unsigned short* __restrict__ part, const int* __restrict__ rowptr,
    int* __restrict__ col, int n_nodes, int n_edges, int n_pad)
{
    __shared__ int cur[BUCKET];
    const int c = blockIdx.x, b = blockIdx.y;
    const int base = b << BUCKET_BITS;
    const int lim = min(BUCKET, n_nodes - base);

    const unsigned short* prow = part + (size_t)(CHUNKS + c) * n_pad + base;
    const int* rp = rowptr + base;
    for (int i = threadIdx.x; i < lim; i += 256)
        cur[i] = rp[i] + (int)prow[i];
    __syncthreads();

    const int ebeg = (int)((long long)n_edges * c / CHUNKS);
    const int eend = (int)((long long)n_edges * (c + 1) / CHUNKS);
    for (int e = ebeg + threadIdx.x; e < eend; e += 256) {
        unsigned v = (unsigned)(dst[e] - base);
        if (v < (unsigned)BUCKET) {
            int pos = atomicAdd(&cur[v], 1);
            col[pos] = src[e];
        }
    }
}

// ---------------- GEMM: h = (x * norm_src) @ W ----------------
__global__ __launch_bounds__(256) void gemm_norm_kernel(
    const float* __restrict__ x, const float* __restrict__ W,
    const int* __restrict__ outdeg, float* __restrict__ h, int n_nodes)
{
    __shared__ float xs[64][68];
    __shared__ float wt[64][68];

    const int tid = threadIdx.x;
    const int ty = tid >> 4;
    const int tx = tid & 15;
    const int r0 = blockIdx.x * 64;

    float acc[4][4] = {};

    for (int k0 = 0; k0 < DIN; k0 += 64) {
        #pragma unroll
        for (int i = 0; i < 4; ++i) {
            int row = (tid >> 4) + 16 * i;
            int c4  = tid & 15;
            int grow = r0 + row;
            float4 v = make_float4(0.f, 0.f, 0.f, 0.f);
            if (grow < n_nodes)
                v = *reinterpret_cast<const float4*>(&x[(size_t)grow * DIN + k0 + c4 * 4]);
            *reinterpret_cast<float4*>(&xs[row][c4 * 4]) = v;
        }
        #pragma unroll
        for (int i = 0; i < 4; ++i) {
            int krow = (tid >> 4) + 16 * i;
            int c4   = tid & 15;
            float4 v = *reinterpret_cast<const float4*>(&W[(size_t)(k0 + krow) * DOUT + c4 * 4]);
            *reinterpret_cast<float4*>(&wt[krow][c4 * 4]) = v;
        }
        __syncthreads();

        #pragma unroll
        for (int k = 0; k < 64; ++k) {
            float a[4], bb[4];
            #pragma unroll
            for (int i = 0; i < 4; ++i) a[i] = xs[ty * 4 + i][k];
            #pragma unroll
            for (int j = 0; j < 4; ++j) bb[j] = wt[k][tx * 4 + j];
            #pragma unroll
            for (int i = 0; i < 4; ++i)
                #pragma unroll
                for (int j = 0; j < 4; ++j)
                    acc[i][j] = fmaf(a[i], bb[j], acc[i][j]);
        }
        __syncthreads();
    }

    #pragma unroll
    for (int i = 0; i < 4; ++i) {
        int grow = r0 + ty * 4 + i;
        if (grow >= n_nodes) continue;
        float ns = rsqrtf(fmaxf((float)outdeg[grow], 1.0f));
        float4 v = make_float4(acc[i][0] * ns, acc[i][1] * ns, acc[i][2] * ns, acc[i][3] * ns);
        *reinterpret_cast<float4*>(&h[(size_t)grow * DOUT + tx * 4]) = v;
    }
}

// ---------------- gather + finalize: one wave per dst node, lane = column ----------------
__global__ __launch_bounds__(256) void gather_kernel(
    const float* __restrict__ h, const int* __restrict__ rowptr,
    const int* __restrict__ col, const float* __restrict__ bias,
    float* __restrict__ out, int n_nodes)
{
    int wave = (blockIdx.x * blockDim.x + threadIdx.x) >> 6;
    int lane = threadIdx.x & 63;
    if (wave >= n_nodes) return;

    const int beg = rowptr[wave];
    const int end = rowptr[wave + 1];
    const int deg = end - beg;

    float acc = 0.f;
    int i = beg;
    for (; i + 4 <= end; i += 4) {
        int s0 = col[i], s1 = col[i + 1], s2 = col[i + 2], s3 = col[i + 3];
        float v0 = h[(size_t)s0 * DOUT + lane];
        float v1 = h[(size_t)s1 * DOUT + lane];
        float v2 = h[(size_t)s2 * DOUT + lane];
        float v3 = h[(size_t)s3 * DOUT + lane];
        acc += (v0 + v1) + (v2 + v3);
    }
    for (; i < end; ++i) {
        acc += h[(size_t)col[i] * DOUT + lane];
    }

    float nd = rsqrtf(fmaxf((float)deg, 1.0f));
    out[(size_t)wave * DOUT + lane] = fmaxf(fmaf(acc, nd, bias[lane]), 0.f);
}

extern "C" void kernel_launch(void* const* d_in, const int* in_sizes, int n_in,
                              void* d_out, int out_size, void* d_ws, size_t ws_size,
                              hipStream_t stream) {
    const float* x   = (const float*)d_in[0];
    const float* W   = (const float*)d_in[1];
    const float* b   = (const float*)d_in[2];
    const int*   src = (const int*)d_in[3];
    const int*   dst = (const int*)d_in[4];
    float* out = (float*)d_out;

    const int n_nodes = in_sizes[0] / DIN;   // 50000
    const int n_edges = in_sizes[3];         // 800000
    const int nsb = (n_nodes + SCAN_BLK - 1) / SCAN_BLK;         // 196
    const int nbuck = (n_nodes + BUCKET - 1) >> BUCKET_BITS;     // 4
    const int n_pad = ((n_nodes + 63) / 64) * 64;                // 50048

    // workspace layout
    int* outdeg = (int*)d_ws;                  // n
    int* indeg  = outdeg + n_nodes;            // n
    int* rowptr = indeg + n_nodes;             // n+1
    int* bsum   = rowptr + n_nodes + 1;        // 256
    int* boff   = bsum + 256;                  // 256
    int* col    = boff + 256;                  // n_edges
    size_t int_count = (size_t)3 * n_nodes + 1 + 512 + n_edges;
    size_t h_off = ((int_count * sizeof(int) + 15) / 16) * 16;
    // shared region: u16 partials (2*CHUNKS*n_pad = ~12.8 MB) aliased with h (12.8 MB).
    // Safe: hist -> reduce -> fill all complete (stream-serialized) before gemm writes h.
    float* h = (float*)((char*)d_ws + h_off);
    unsigned short* part = (unsigned short*)h;

    hist_kernel<<<dim3(CHUNKS, nbuck, 2), 256, 0, stream>>>(src, dst, part, n_nodes, n_edges, n_pad);
    reduce_deg_kernel<<<(n_nodes + 255) / 256, 256, 0, stream>>>(part, outdeg, indeg, n_nodes, n_pad);
    partial_kernel<<<nsb, SCAN_BLK, 0, stream>>>(indeg, bsum, n_nodes);
    scan_bsums_kernel<<<1, 256, 0, stream>>>(bsum, boff, nsb);
    emit_kernel<<<nsb, SCAN_BLK, 0, stream>>>(indeg, boff, rowptr, n_nodes, n_edges);
    fill_kernel<<<dim3(CHUNKS, nbuck), 256, 0, stream>>>(src, dst, part, rowptr, col, n_nodes, n_edges, n_pad);
    gemm_norm_kernel<<<(n_nodes + 63) / 64, 256, 0, stream>>>(x, W, outdeg, h, n_nodes);
    gather_kernel<<<((size_t)n_nodes * 64 + 255) / 256, 256, 0, stream>>>(h, rowptr, col, b, out, n_nodes);
}

// Round 6
// 122.335 us; speedup vs baseline: 1.9552x; 1.2058x over previous
//
#include <hip/hip_runtime.h>
#include <hip/hip_fp16.h>

#define DIN 256
#define DOUT 64
#define SCAN_BLK 256
#define BUCKET_BITS 14
#define BUCKET (1 << BUCKET_BITS)   // 16384 nodes per LDS bucket (64 KB)
#define CHUNKS 64                   // edge chunks -> fill grid = CHUNKS x nbuck = 256 blocks
#define BM 128

using half8 = __attribute__((ext_vector_type(8))) _Float16;
using f32x4 = __attribute__((ext_vector_type(4))) float;

// ---------------- histogram: per-(chunk,bucket,array) LDS-private counts -> u16 partials ----------------
__global__ __launch_bounds__(256) void hist_kernel(
    const int* __restrict__ src, const int* __restrict__ dst,
    unsigned short* __restrict__ part, int n_nodes, int n_edges, int n_pad)
{
    __shared__ int cnt[BUCKET];
    const int c = blockIdx.x, b = blockIdx.y, a = blockIdx.z;
    const int* __restrict__ idx = a ? dst : src;
    const int base = b << BUCKET_BITS;

    for (int i = threadIdx.x; i < BUCKET; i += 256) cnt[i] = 0;
    __syncthreads();

    const int ebeg = (int)((long long)n_edges * c / CHUNKS);
    const int eend = (int)((long long)n_edges * (c + 1) / CHUNKS);
    for (int e = ebeg + threadIdx.x; e < eend; e += 256) {
        unsigned v = (unsigned)(idx[e] - base);
        if (v < (unsigned)BUCKET) atomicAdd(&cnt[v], 1);
    }
    __syncthreads();

    const int lim = min(BUCKET, n_nodes - base);
    unsigned short* row = part + (size_t)(a * CHUNKS + c) * n_pad + base;
    for (int i = threadIdx.x; i < lim; i += 256) row[i] = (unsigned short)cnt[i];
}

// ---------------- reduce partials -> outdeg; in-place excl prefix over dst rows -> indeg ----------------
__global__ __launch_bounds__(256) void reduce_deg_kernel(
    unsigned short* __restrict__ part, int* __restrict__ outdeg,
    int* __restrict__ indeg, int n_nodes, int n_pad)
{
    int i = blockIdx.x * 256 + threadIdx.x;
    if (i >= n_nodes) return;
    int s0 = 0;
    #pragma unroll
    for (int c = 0; c < CHUNKS; ++c) s0 += part[(size_t)c * n_pad + i];
    outdeg[i] = s0;
    int run = 0;
    #pragma unroll
    for (int c = 0; c < CHUNKS; ++c) {
        size_t off = (size_t)(CHUNKS + c) * n_pad + i;
        int t = part[off];
        part[off] = (unsigned short)run;
        run += t;
    }
    indeg[i] = run;
}

// ---------------- scan phase 1: per-block sums ----------------
__global__ __launch_bounds__(SCAN_BLK) void partial_kernel(
    const int* __restrict__ indeg, int* __restrict__ bsum, int n)
{
    __shared__ int red[SCAN_BLK / 64];
    int idx = blockIdx.x * SCAN_BLK + threadIdx.x;
    int v = (idx < n) ? indeg[idx] : 0;
    #pragma unroll
    for (int off = 32; off >= 1; off >>= 1)
        v += __shfl_down(v, off, 64);
    int wid = threadIdx.x >> 6;
    if ((threadIdx.x & 63) == 0) red[wid] = v;
    __syncthreads();
    if (threadIdx.x == 0) {
        int s = 0;
        #pragma unroll
        for (int w = 0; w < SCAN_BLK / 64; ++w) s += red[w];
        bsum[blockIdx.x] = s;
    }
}

// ---------------- scan phase 2: exclusive scan of block sums (1 block) ----------------
__global__ __launch_bounds__(256) void scan_bsums_kernel(
    int* __restrict__ bsum, int* __restrict__ boff, int nblocks)
{
    __shared__ int s[256];
    int t = threadIdx.x;
    int v = (t < nblocks) ? bsum[t] : 0;
    s[t] = v;
    __syncthreads();
    for (int off = 1; off < 256; off <<= 1) {
        int u = 0;
        if (t >= off) u = s[t - off];
        __syncthreads();
        if (t >= off) s[t] += u;
        __syncthreads();
    }
    if (t < nblocks) boff[t] = s[t] - v;  // exclusive
}

// ---------------- scan phase 3: emit rowptr ----------------
__global__ __launch_bounds__(SCAN_BLK) void emit_kernel(
    const int* __restrict__ indeg, const int* __restrict__ boff,
    int* __restrict__ rowptr, int n, int n_edges)
{
    __shared__ int s[SCAN_BLK];
    int t = threadIdx.x;
    int idx = blockIdx.x * SCAN_BLK + t;
    int v = (idx < n) ? indeg[idx] : 0;
    s[t] = v;
    __syncthreads();
    for (int off = 1; off < SCAN_BLK; off <<= 1) {
        int u = 0;
        if (t >= off) u = s[t - off];
        __syncthreads();
        if (t >= off) s[t] += u;
        __syncthreads();
    }
    if (idx < n) rowptr[idx] = boff[blockIdx.x] + s[t] - v;
    if (idx == 0) rowptr[n] = n_edges;
}

// ---------------- W (f32 [256][64]) -> W^T fp16 [64][256] ----------------
__global__ __launch_bounds__(256) void convert_w_kernel(
    const float* __restrict__ W, unsigned short* __restrict__ w16t)
{
    int idx = blockIdx.x * 256 + threadIdx.x;   // 16384 threads
    int n = idx & 63, k = idx >> 6;
    __half v = __float2half(W[k * DOUT + n]);
    w16t[n * DIN + k] = *(unsigned short*)&v;
}

// ---------------- CSR fill via LDS cursor multisplit ----------------
__global__ __launch_bounds__(256) void fill_kernel(
    const int* __restrict__ src, const int* __restrict__ dst,
    const unsigned short* __restrict__ part, const int* __restrict__ rowptr,
    int* __restrict__ col, int n_nodes, int n_edges, int n_pad)
{
    __shared__ int cur[BUCKET];
    const int c = blockIdx.x, b = blockIdx.y;
    const int base = b << BUCKET_BITS;
    const int lim = min(BUCKET, n_nodes - base);

    const unsigned short* prow = part + (size_t)(CHUNKS + c) * n_pad + base;
    const int* rp = rowptr + base;
    for (int i = threadIdx.x; i < lim; i += 256)
        cur[i] = rp[i] + (int)prow[i];
    __syncthreads();

    const int ebeg = (int)((long long)n_edges * c / CHUNKS);
    const int eend = (int)((long long)n_edges * (c + 1) / CHUNKS);
    for (int e = ebeg + threadIdx.x; e < eend; e += 256) {
        unsigned v = (unsigned)(dst[e] - base);
        if (v < (unsigned)BUCKET) {
            int pos = atomicAdd(&cur[v], 1);
            col[pos] = src[e];
        }
    }
}

// ---------------- MFMA GEMM: h_fp16 = (x * norm_src) @ W ----------------
// 128x64 block tile, 4 waves; wave = 32 rows x 64 cols via 2x4 16x16 tiles.
// x converted f32->fp16 during LDS staging; XOR-swizzled LDS (T2) for ds_read_b128.
__global__ __launch_bounds__(256) void gemm_mfma_kernel(
    const float* __restrict__ x, const unsigned short* __restrict__ w16t,
    const int* __restrict__ outdeg, __half* __restrict__ h, int n_nodes)
{
    __shared__ unsigned char Abuf[BM * 128];   // [128 rows][64 halves = 128 B], swizzled
    __shared__ unsigned char Bbuf[64 * 512];   // [64 cols][256 halves = 512 B], swizzled

    const int tid = threadIdx.x;
    const int r0 = blockIdx.x * BM;
    const int w = tid >> 6;
    const int lane = tid & 63;
    const int l16 = lane & 15;
    const int kg = lane >> 4;   // 0..3 (k-group of 8)

    // stage B once: 64*32 uint4 units, 8 per thread
    {
        const uint4* srcB = (const uint4*)w16t;
        for (int u = tid; u < 64 * 32; u += 256) {
            int c = u >> 5, q = u & 31;
            uint4 v = srcB[u];
            int byte = (c << 9) + (q << 4);
            byte ^= ((c & 7) << 4);
            *(uint4*)(Bbuf + byte) = v;
        }
    }

    f32x4 acc[2][4] = {{{0.f,0.f,0.f,0.f}}};

    for (int k0 = 0; k0 < 4; ++k0) {
        if (k0) __syncthreads();   // drain previous compute before overwriting Abuf
        // stage A: 128 rows x 64 k (f32 -> fp16); unit = float4: 2048 units, 8/thread
        for (int u = tid; u < BM * 16; u += 256) {
            int row = u >> 4, fq = u & 15;
            int grow = r0 + row;
            float4 v = make_float4(0.f, 0.f, 0.f, 0.f);
            if (grow < n_nodes)
                v = *(const float4*)(&x[(size_t)grow * DIN + (k0 << 6) + (fq << 2)]);
            __half2 p0 = __floats2half2_rn(v.x, v.y);
            __half2 p1 = __floats2half2_rn(v.z, v.w);
            int byte = (row << 7) + (fq << 3);
            byte ^= ((row & 7) << 4);
            *(__half2*)(Abuf + byte) = p0;
            *(__half2*)(Abuf + byte + 4) = p1;
        }
        __syncthreads();

        #pragma unroll
        for (int ks = 0; ks < 2; ++ks) {
            half8 a[2], b[4];
            #pragma unroll
            for (int rt = 0; rt < 2; ++rt) {
                int row = (w << 5) + (rt << 4) + l16;
                int byte = (row << 7) + (ks << 6) + (kg << 4);
                byte ^= ((row & 7) << 4);
                a[rt] = *(const half8*)(Abuf + byte);
            }
            #pragma unroll
            for (int ct = 0; ct < 4; ++ct) {
                int c = (ct << 4) + l16;
                int byte = (c << 9) + (k0 << 7) + (ks << 6) + (kg << 4);
                byte ^= ((c & 7) << 4);
                b[ct] = *(const half8*)(Bbuf + byte);
            }
            #pragma unroll
            for (int rt = 0; rt < 2; ++rt)
                #pragma unroll
                for (int ct = 0; ct < 4; ++ct)
                    acc[rt][ct] = __builtin_amdgcn_mfma_f32_16x16x32_f16(a[rt], b[ct], acc[rt][ct], 0, 0, 0);
        }
    }

    // epilogue: C/D layout col = l16 (+16*ct), row = 4*kg + reg (verified m89/m91)
    #pragma unroll
    for (int rt = 0; rt < 2; ++rt) {
        #pragma unroll
        for (int reg = 0; reg < 4; ++reg) {
            int grow = r0 + (w << 5) + (rt << 4) + (kg << 2) + reg;
            if (grow < n_nodes) {
                float ns = rsqrtf(fmaxf((float)outdeg[grow], 1.0f));
                #pragma unroll
                for (int ct = 0; ct < 4; ++ct)
                    h[(size_t)grow * DOUT + (ct << 4) + l16] = __float2half(acc[rt][ct][reg] * ns);
            }
        }
    }
}

// ---------------- gather + finalize: one wave per dst node, 4 edges/iter ----------------
// 16 lanes per edge-slot; lane l16 covers cols 4*l16..4*l16+3 (8 B fp16 loads).
__global__ __launch_bounds__(256) void gather_kernel(
    const __half* __restrict__ h, const int* __restrict__ rowptr,
    const int* __restrict__ col, const float* __restrict__ bias,
    float* __restrict__ out, int n_nodes)
{
    int wid = (blockIdx.x * blockDim.x + threadIdx.x) >> 6;
    int lane = threadIdx.x & 63;
    if (wid >= n_nodes) return;
    const int g = lane >> 4, l16 = lane & 15;

    const int beg = rowptr[wid];
    const int end = rowptr[wid + 1];
    const int deg = end - beg;

    float4 acc = make_float4(0.f, 0.f, 0.f, 0.f);
    #pragma unroll 2
    for (int i = beg + g; i < end; i += 4) {
        int s = col[i];
        uint2 v = *(const uint2*)((const char*)h + ((size_t)s << 7) + (l16 << 3));
        __half2 p0 = *(__half2*)&v.x;
        __half2 p1 = *(__half2*)&v.y;
        float2 a = __half22float2(p0);
        float2 b2 = __half22float2(p1);
        acc.x += a.x; acc.y += a.y; acc.z += b2.x; acc.w += b2.y;
    }

    // combine the 4 edge-groups: xor 16 then 32
    acc.x += __shfl_xor(acc.x, 16, 64); acc.y += __shfl_xor(acc.y, 16, 64);
    acc.z += __shfl_xor(acc.z, 16, 64); acc.w += __shfl_xor(acc.w, 16, 64);
    acc.x += __shfl_xor(acc.x, 32, 64); acc.y += __shfl_xor(acc.y, 32, 64);
    acc.z += __shfl_xor(acc.z, 32, 64); acc.w += __shfl_xor(acc.w, 32, 64);

    if (g == 0) {
        float nd = rsqrtf(fmaxf((float)deg, 1.0f));
        float4 bb = *(const float4*)(&bias[l16 * 4]);
        float4 o;
        o.x = fmaxf(fmaf(acc.x, nd, bb.x), 0.f);
        o.y = fmaxf(fmaf(acc.y, nd, bb.y), 0.f);
        o.z = fmaxf(fmaf(acc.z, nd, bb.z), 0.f);
        o.w = fmaxf(fmaf(acc.w, nd, bb.w), 0.f);
        *(float4*)(&out[((size_t)wid << 6) + l16 * 4]) = o;
    }
}

extern "C" void kernel_launch(void* const* d_in, const int* in_sizes, int n_in,
                              void* d_out, int out_size, void* d_ws, size_t ws_size,
                              hipStream_t stream) {
    const float* x   = (const float*)d_in[0];
    const float* W   = (const float*)d_in[1];
    const float* b   = (const float*)d_in[2];
    const int*   src = (const int*)d_in[3];
    const int*   dst = (const int*)d_in[4];
    float* out = (float*)d_out;

    const int n_nodes = in_sizes[0] / DIN;   // 50000
    const int n_edges = in_sizes[3];         // 800000
    const int nsb = (n_nodes + SCAN_BLK - 1) / SCAN_BLK;         // 196
    const int nbuck = (n_nodes + BUCKET - 1) >> BUCKET_BITS;     // 4
    const int n_pad = ((n_nodes + 63) / 64) * 64;                // 50048

    // workspace layout
    int* outdeg = (int*)d_ws;                  // n
    int* indeg  = outdeg + n_nodes;            // n (reused as w16t after emit)
    int* rowptr = indeg + n_nodes;             // n+1
    int* bsum   = rowptr + n_nodes + 1;        // 256
    int* boff   = bsum + 256;                  // 256
    int* col    = boff + 256;                  // n_edges
    size_t int_count = (size_t)3 * n_nodes + 1 + 512 + n_edges;
    size_t h_off = ((int_count * sizeof(int) + 15) / 16) * 16;
    // shared region: u16 partials (2*CHUNKS*n_pad ~ 12.8 MB) aliased with h fp16 (6.4 MB).
    // Safe: hist -> reduce -> fill complete (stream-serialized) before gemm writes h.
    __half* h = (__half*)((char*)d_ws + h_off);
    unsigned short* part = (unsigned short*)h;
    unsigned short* w16t = (unsigned short*)indeg;   // 32 KB, written after emit's last indeg read

    hist_kernel<<<dim3(CHUNKS, nbuck, 2), 256, 0, stream>>>(src, dst, part, n_nodes, n_edges, n_pad);
    reduce_deg_kernel<<<(n_nodes + 255) / 256, 256, 0, stream>>>(part, outdeg, indeg, n_nodes, n_pad);
    partial_kernel<<<nsb, SCAN_BLK, 0, stream>>>(indeg, bsum, n_nodes);
    scan_bsums_kernel<<<1, 256, 0, stream>>>(bsum, boff, nsb);
    emit_kernel<<<nsb, SCAN_BLK, 0, stream>>>(indeg, boff, rowptr, n_nodes, n_edges);
    convert_w_kernel<<<(DIN * DOUT) / 256, 256, 0, stream>>>(W, w16t);
    fill_kernel<<<dim3(CHUNKS, nbuck), 256, 0, stream>>>(src, dst, part, rowptr, col, n_nodes, n_edges, n_pad);
    gemm_mfma_kernel<<<(n_nodes + BM - 1) / BM, 256, 0, stream>>>(x, w16t, outdeg, h, n_nodes);
    gather_kernel<<<((size_t)n_nodes * 64 + 255) / 256, 256, 0, stream>>>(h, rowptr, col, b, out, n_nodes);
}

// Round 7
// 106.806 us; speedup vs baseline: 2.2395x; 1.1454x over previous
//
#include <hip/hip_runtime.h>
#include <hip/hip_fp16.h>

#define DIN 256
#define DOUT 64
#define SCAN_BLK 256
#define BUCKET_BITS 14
#define BUCKET (1 << BUCKET_BITS)   // 16384 nodes per LDS bucket (64 KB)
#define CHUNKS 64                   // edge chunks -> fill grid = CHUNKS x nbuck = 256 blocks
#define BM 128

using half8 = __attribute__((ext_vector_type(8))) _Float16;
using f32x4 = __attribute__((ext_vector_type(4))) float;

// ---------------- histogram: per-(chunk,bucket,array) LDS-private counts -> u16 partials ----------------
__global__ __launch_bounds__(256) void hist_kernel(
    const int* __restrict__ src, const int* __restrict__ dst,
    unsigned short* __restrict__ part, int n_nodes, int n_edges, int n_pad)
{
    __shared__ int cnt[BUCKET];
    const int c = blockIdx.x, b = blockIdx.y, a = blockIdx.z;
    const int* __restrict__ idx = a ? dst : src;
    const int base = b << BUCKET_BITS;

    for (int i = threadIdx.x; i < BUCKET; i += 256) cnt[i] = 0;
    __syncthreads();

    const int ebeg = (int)((long long)n_edges * c / CHUNKS);
    const int eend = (int)((long long)n_edges * (c + 1) / CHUNKS);
    const int nvec = (eend - ebeg) >> 2;
    const int4* idx4 = (const int4*)(idx + ebeg);   // ebeg is 4-aligned (12500*c)
    for (int q = threadIdx.x; q < nvec; q += 256) {
        int4 e4 = idx4[q];
        unsigned v0 = (unsigned)(e4.x - base);
        unsigned v1 = (unsigned)(e4.y - base);
        unsigned v2 = (unsigned)(e4.z - base);
        unsigned v3 = (unsigned)(e4.w - base);
        if (v0 < (unsigned)BUCKET) atomicAdd(&cnt[v0], 1);
        if (v1 < (unsigned)BUCKET) atomicAdd(&cnt[v1], 1);
        if (v2 < (unsigned)BUCKET) atomicAdd(&cnt[v2], 1);
        if (v3 < (unsigned)BUCKET) atomicAdd(&cnt[v3], 1);
    }
    for (int e = ebeg + (nvec << 2) + threadIdx.x; e < eend; e += 256) {
        unsigned v = (unsigned)(idx[e] - base);
        if (v < (unsigned)BUCKET) atomicAdd(&cnt[v], 1);
    }
    __syncthreads();

    const int lim = min(BUCKET, n_nodes - base);
    unsigned short* row = part + (size_t)(a * CHUNKS + c) * n_pad + base;
    for (int i = threadIdx.x; i < lim; i += 256) row[i] = (unsigned short)cnt[i];
}

// ---------------- reduce partials -> outdeg/indeg, in-place prefix; fused per-block sum -> bsum ----------------
__global__ __launch_bounds__(256) void reduce_scan1_kernel(
    unsigned short* __restrict__ part, int* __restrict__ outdeg,
    int* __restrict__ indeg, int* __restrict__ bsum, int n_nodes, int n_pad)
{
    __shared__ int red[4];
    int i = blockIdx.x * 256 + threadIdx.x;
    int run = 0;
    if (i < n_nodes) {
        int s0 = 0;
        #pragma unroll
        for (int c = 0; c < CHUNKS; ++c) s0 += part[(size_t)c * n_pad + i];
        outdeg[i] = s0;
        #pragma unroll
        for (int c = 0; c < CHUNKS; ++c) {
            size_t off = (size_t)(CHUNKS + c) * n_pad + i;
            int t = part[off];
            part[off] = (unsigned short)run;
            run += t;
        }
        indeg[i] = run;
    }
    // block-reduce run -> bsum[blockIdx.x]
    int v = run;
    #pragma unroll
    for (int off = 32; off >= 1; off >>= 1)
        v += __shfl_down(v, off, 64);
    if ((threadIdx.x & 63) == 0) red[threadIdx.x >> 6] = v;
    __syncthreads();
    if (threadIdx.x == 0)
        bsum[blockIdx.x] = red[0] + red[1] + red[2] + red[3];
}

// ---------------- scan of block sums (block 0) + W conversion (blocks 1..64) ----------------
__global__ __launch_bounds__(256) void scan_convw_kernel(
    int* __restrict__ bsum, int* __restrict__ boff, int nblocks,
    const float* __restrict__ W, unsigned short* __restrict__ w16t)
{
    if (blockIdx.x == 0) {
        __shared__ int s[256];
        int t = threadIdx.x;
        int v = (t < nblocks) ? bsum[t] : 0;
        s[t] = v;
        __syncthreads();
        for (int off = 1; off < 256; off <<= 1) {
            int u = 0;
            if (t >= off) u = s[t - off];
            __syncthreads();
            if (t >= off) s[t] += u;
            __syncthreads();
        }
        if (t < nblocks) boff[t] = s[t] - v;  // exclusive
    } else {
        int idx = (blockIdx.x - 1) * 256 + threadIdx.x;   // 0..16383
        int n = idx & 63, k = idx >> 6;
        __half v = __float2half(W[k * DOUT + n]);
        w16t[n * DIN + k] = *(unsigned short*)&v;
    }
}

// ---------------- emit rowptr ----------------
__global__ __launch_bounds__(SCAN_BLK) void emit_kernel(
    const int* __restrict__ indeg, const int* __restrict__ boff,
    int* __restrict__ rowptr, int n, int n_edges)
{
    __shared__ int s[SCAN_BLK];
    int t = threadIdx.x;
    int idx = blockIdx.x * SCAN_BLK + t;
    int v = (idx < n) ? indeg[idx] : 0;
    s[t] = v;
    __syncthreads();
    for (int off = 1; off < SCAN_BLK; off <<= 1) {
        int u = 0;
        if (t >= off) u = s[t - off];
        __syncthreads();
        if (t >= off) s[t] += u;
        __syncthreads();
    }
    if (idx < n) rowptr[idx] = boff[blockIdx.x] + s[t] - v;
    if (idx == 0) rowptr[n] = n_edges;
}

// ---------------- CSR fill via LDS cursor multisplit (int4 edge loads) ----------------
__global__ __launch_bounds__(256) void fill_kernel(
    const int* __restrict__ src, const int* __restrict__ dst,
    const unsigned short* __restrict__ part, const int* __restrict__ rowptr,
    int* __restrict__ col, int n_nodes, int n_edges, int n_pad)
{
    __shared__ int cur[BUCKET];
    const int c = blockIdx.x, b = blockIdx.y;
    const int base = b << BUCKET_BITS;
    const int lim = min(BUCKET, n_nodes - base);

    const unsigned short* prow = part + (size_t)(CHUNKS + c) * n_pad + base;
    const int* rp = rowptr + base;
    for (int i = threadIdx.x; i < lim; i += 256)
        cur[i] = rp[i] + (int)prow[i];
    __syncthreads();

    const int ebeg = (int)((long long)n_edges * c / CHUNKS);
    const int eend = (int)((long long)n_edges * (c + 1) / CHUNKS);
    const int nvec = (eend - ebeg) >> 2;
    const int4* dst4 = (const int4*)(dst + ebeg);
    const int4* src4 = (const int4*)(src + ebeg);
    for (int q = threadIdx.x; q < nvec; q += 256) {
        int4 d4 = dst4[q];
        int4 s4 = src4[q];
        unsigned v0 = (unsigned)(d4.x - base);
        unsigned v1 = (unsigned)(d4.y - base);
        unsigned v2 = (unsigned)(d4.z - base);
        unsigned v3 = (unsigned)(d4.w - base);
        if (v0 < (unsigned)BUCKET) col[atomicAdd(&cur[v0], 1)] = s4.x;
        if (v1 < (unsigned)BUCKET) col[atomicAdd(&cur[v1], 1)] = s4.y;
        if (v2 < (unsigned)BUCKET) col[atomicAdd(&cur[v2], 1)] = s4.z;
        if (v3 < (unsigned)BUCKET) col[atomicAdd(&cur[v3], 1)] = s4.w;
    }
    for (int e = ebeg + (nvec << 2) + threadIdx.x; e < eend; e += 256) {
        unsigned v = (unsigned)(dst[e] - base);
        if (v < (unsigned)BUCKET) col[atomicAdd(&cur[v], 1)] = src[e];
    }
}

// ---------------- MFMA GEMM: h (two fp16 column-planes) = (x * norm_src) @ W ----------------
// 128x64 block tile, 4 waves; wave = 32 rows x 64 cols via 2x4 16x16 tiles.
__global__ __launch_bounds__(256) void gemm_mfma_kernel(
    const float* __restrict__ x, const unsigned short* __restrict__ w16t,
    const int* __restrict__ outdeg, __half* __restrict__ h,
    int n_nodes, size_t plane_elems)
{
    __shared__ unsigned char Abuf[BM * 128];   // [128 rows][64 halves = 128 B], swizzled
    __shared__ unsigned char Bbuf[64 * 512];   // [64 cols][256 halves = 512 B], swizzled

    const int tid = threadIdx.x;
    const int r0 = blockIdx.x * BM;
    const int w = tid >> 6;
    const int lane = tid & 63;
    const int l16 = lane & 15;
    const int kg = lane >> 4;   // 0..3 (k-group of 8)

    // stage B once: 64*32 uint4 units, 8 per thread
    {
        const uint4* srcB = (const uint4*)w16t;
        for (int u = tid; u < 64 * 32; u += 256) {
            int c = u >> 5, q = u & 31;
            uint4 v = srcB[u];
            int byte = (c << 9) + (q << 4);
            byte ^= ((c & 7) << 4);
            *(uint4*)(Bbuf + byte) = v;
        }
    }

    f32x4 acc[2][4] = {{{0.f,0.f,0.f,0.f}}};

    for (int k0 = 0; k0 < 4; ++k0) {
        if (k0) __syncthreads();   // drain previous compute before overwriting Abuf
        // stage A: 128 rows x 64 k (f32 -> fp16); unit = float4: 2048 units, 8/thread
        for (int u = tid; u < BM * 16; u += 256) {
            int row = u >> 4, fq = u & 15;
            int grow = r0 + row;
            float4 v = make_float4(0.f, 0.f, 0.f, 0.f);
            if (grow < n_nodes)
                v = *(const float4*)(&x[(size_t)grow * DIN + (k0 << 6) + (fq << 2)]);
            __half2 p0 = __floats2half2_rn(v.x, v.y);
            __half2 p1 = __floats2half2_rn(v.z, v.w);
            uint2 wv;
            wv.x = *(unsigned int*)&p0;
            wv.y = *(unsigned int*)&p1;
            int byte = (row << 7) + (fq << 3);
            byte ^= ((row & 7) << 4);
            *(uint2*)(Abuf + byte) = wv;
        }
        __syncthreads();

        #pragma unroll
        for (int ks = 0; ks < 2; ++ks) {
            half8 a[2], b[4];
            #pragma unroll
            for (int rt = 0; rt < 2; ++rt) {
                int row = (w << 5) + (rt << 4) + l16;
                int byte = (row << 7) + (ks << 6) + (kg << 4);
                byte ^= ((row & 7) << 4);
                a[rt] = *(const half8*)(Abuf + byte);
            }
            #pragma unroll
            for (int ct = 0; ct < 4; ++ct) {
                int c = (ct << 4) + l16;
                int byte = (c << 9) + (k0 << 7) + (ks << 6) + (kg << 4);
                byte ^= ((c & 7) << 4);
                b[ct] = *(const half8*)(Bbuf + byte);
            }
            #pragma unroll
            for (int rt = 0; rt < 2; ++rt)
                #pragma unroll
                for (int ct = 0; ct < 4; ++ct)
                    acc[rt][ct] = __builtin_amdgcn_mfma_f32_16x16x32_f16(a[rt], b[ct], acc[rt][ct], 0, 0, 0);
        }
    }

    // epilogue: C/D layout col = l16 (+16*ct), row = 4*kg + reg; split cols into 2 planes of 32
    #pragma unroll
    for (int rt = 0; rt < 2; ++rt) {
        #pragma unroll
        for (int reg = 0; reg < 4; ++reg) {
            int grow = r0 + (w << 5) + (rt << 4) + (kg << 2) + reg;
            if (grow < n_nodes) {
                float ns = rsqrtf(fmaxf((float)outdeg[grow], 1.0f));
                #pragma unroll
                for (int ct = 0; ct < 4; ++ct) {
                    int colp = ((ct & 1) << 4) + l16;   // 0..31 within plane
                    __half* hp = h + (size_t)(ct >> 1) * plane_elems + ((size_t)grow << 5) + colp;
                    *hp = __float2half(acc[rt][ct][reg] * ns);
                }
            }
        }
    }
}

// ---------------- gather one 32-col plane: wave per dst node, 8 edges/iter ----------------
// 8 lanes per edge-slot; lane l8 covers plane cols 4*l8..4*l8+3 (8 B fp16 loads).
__global__ __launch_bounds__(256) void gather_kernel(
    const __half* __restrict__ h, const int* __restrict__ rowptr,
    const int* __restrict__ col, const float* __restrict__ bias,
    float* __restrict__ out, int n_nodes, size_t plane_elems, int plane)
{
    int wid = (blockIdx.x * blockDim.x + threadIdx.x) >> 6;
    int lane = threadIdx.x & 63;
    if (wid >= n_nodes) return;
    const int g = lane >> 3, l8 = lane & 7;

    const int beg = rowptr[wid];
    const int end = rowptr[wid + 1];
    const int deg = end - beg;

    const char* hbase = (const char*)(h + (size_t)plane * plane_elems) + (l8 << 3);

    float4 acc = make_float4(0.f, 0.f, 0.f, 0.f);
    #pragma unroll 2
    for (int i = beg + g; i < end; i += 8) {
        int s = col[i];
        uint2 v = *(const uint2*)(hbase + ((size_t)s << 6));
        __half2 p0 = *(__half2*)&v.x;
        __half2 p1 = *(__half2*)&v.y;
        float2 a = __half22float2(p0);
        float2 b2 = __half22float2(p1);
        acc.x += a.x; acc.y += a.y; acc.z += b2.x; acc.w += b2.y;
    }

    // combine the 8 edge-groups: xor 8, 16, 32
    #pragma unroll
    for (int d = 8; d <= 32; d <<= 1) {
        acc.x += __shfl_xor(acc.x, d, 64);
        acc.y += __shfl_xor(acc.y, d, 64);
        acc.z += __shfl_xor(acc.z, d, 64);
        acc.w += __shfl_xor(acc.w, d, 64);
    }

    if (g == 0) {
        float nd = rsqrtf(fmaxf((float)deg, 1.0f));
        int c0 = (plane << 5) + (l8 << 2);
        float4 bb = *(const float4*)(&bias[c0]);
        float4 o;
        o.x = fmaxf(fmaf(acc.x, nd, bb.x), 0.f);
        o.y = fmaxf(fmaf(acc.y, nd, bb.y), 0.f);
        o.z = fmaxf(fmaf(acc.z, nd, bb.z), 0.f);
        o.w = fmaxf(fmaf(acc.w, nd, bb.w), 0.f);
        *(float4*)(&out[((size_t)wid << 6) + c0]) = o;
    }
}

extern "C" void kernel_launch(void* const* d_in, const int* in_sizes, int n_in,
                              void* d_out, int out_size, void* d_ws, size_t ws_size,
                              hipStream_t stream) {
    const float* x   = (const float*)d_in[0];
    const float* W   = (const float*)d_in[1];
    const float* b   = (const float*)d_in[2];
    const int*   src = (const int*)d_in[3];
    const int*   dst = (const int*)d_in[4];
    float* out = (float*)d_out;

    const int n_nodes = in_sizes[0] / DIN;   // 50000
    const int n_edges = in_sizes[3];         // 800000
    const int nsb = (n_nodes + SCAN_BLK - 1) / SCAN_BLK;         // 196
    const int nbuck = (n_nodes + BUCKET - 1) >> BUCKET_BITS;     // 4
    const int n_pad = ((n_nodes + 63) / 64) * 64;                // 50048
    const size_t plane_elems = (size_t)n_pad * 32;               // halves per plane

    // workspace layout (no aliasing; ws is large)
    int* outdeg = (int*)d_ws;                  // n
    int* indeg  = outdeg + n_nodes;            // n
    int* rowptr = indeg + n_nodes;             // n+1
    int* bsum   = rowptr + n_nodes + 1;        // 256
    int* boff   = bsum + 256;                  // 256
    int* w16t_i = boff + 256;                  // 8192 ints = 16384 halves (32 KB)
    int* col    = w16t_i + 8192;               // n_edges
    size_t int_count = (size_t)3 * n_nodes + 1 + 512 + 8192 + n_edges;
    size_t part_off = ((int_count * sizeof(int) + 63) / 64) * 64;
    unsigned short* part = (unsigned short*)((char*)d_ws + part_off);  // 2*CHUNKS*n_pad u16 (~12.8 MB)
    size_t h_off = part_off + ((size_t)2 * CHUNKS * n_pad * sizeof(unsigned short) + 63) / 64 * 64;
    __half* h = (__half*)((char*)d_ws + h_off);                        // 2 planes x n_pad x 32 (~6.4 MB)
    unsigned short* w16t = (unsigned short*)w16t_i;

    hist_kernel<<<dim3(CHUNKS, nbuck, 2), 256, 0, stream>>>(src, dst, part, n_nodes, n_edges, n_pad);
    reduce_scan1_kernel<<<nsb, 256, 0, stream>>>(part, outdeg, indeg, bsum, n_nodes, n_pad);
    scan_convw_kernel<<<1 + 64, 256, 0, stream>>>(bsum, boff, nsb, W, w16t);
    emit_kernel<<<nsb, SCAN_BLK, 0, stream>>>(indeg, boff, rowptr, n_nodes, n_edges);
    fill_kernel<<<dim3(CHUNKS, nbuck), 256, 0, stream>>>(src, dst, part, rowptr, col, n_nodes, n_edges, n_pad);
    gemm_mfma_kernel<<<(n_nodes + BM - 1) / BM, 256, 0, stream>>>(x, w16t, outdeg, h, n_nodes, plane_elems);
    gather_kernel<<<((size_t)n_nodes * 64 + 255) / 256, 256, 0, stream>>>(h, rowptr, col, b, out, n_nodes, plane_elems, 0);
    gather_kernel<<<((size_t)n_nodes * 64 + 255) / 256, 256, 0, stream>>>(h, rowptr, col, b, out, n_nodes, plane_elems, 1);
}